// Round 4
// baseline (356.986 us; speedup 1.0000x reference)
//
#include <hip/hip_runtime.h>
#include <hip/hip_bf16.h>
#include <cstdint>

#define CH 128
// nodes per coarse bucket = 128 (dst >> 7). Packing requires N < 65536.

typedef __attribute__((ext_vector_type(8))) short short8;
typedef __attribute__((ext_vector_type(4))) float f32x4;

union FragU {
  uint4 u;
  short8 s;
  ushort h[8];
};

// ---------------- bf16 helpers ----------------
__device__ __forceinline__ float bf_lo(uint32_t u) { return __uint_as_float(u << 16); }
__device__ __forceinline__ float bf_hi(uint32_t u) { return __uint_as_float(u & 0xffff0000u); }
__device__ __forceinline__ uint32_t f2bf(float f) {  // RNE, result in low 16
  uint32_t u = __float_as_uint(f);
  u += 0x7fff + ((u >> 16) & 1);
  return u >> 16;
}

// ---------------- CSR build (two-level counting sort) ----------------

__global__ __launch_bounds__(256) void k_zero(int* __restrict__ p, int n) {
  int i = blockIdx.x * 256 + threadIdx.x;
  if (i < n) p[i] = 0;
}

// coarse histogram over 391 buckets, LDS-aggregated
__global__ __launch_bounds__(256) void k_hist(const int* __restrict__ dst, int* __restrict__ bcount, int E) {
  __shared__ int sh[512];
  for (int i = threadIdx.x; i < 512; i += 256) sh[i] = 0;
  __syncthreads();
  int base = blockIdx.x * 1024;
  int lim = min(base + 1024, E);
  for (int i = base + threadIdx.x; i < lim; i += 256)
    atomicAdd(&sh[dst[i] >> 7], 1);
  __syncthreads();
  for (int i = threadIdx.x; i < 512; i += 256)
    if (sh[i]) atomicAdd(&bcount[i], sh[i]);
}

// single-block exclusive scan of 512 bucket counts -> bbase, bcursor
__global__ __launch_bounds__(512) void k_scanb(const int* __restrict__ bcount, int* __restrict__ bbase,
                                               int* __restrict__ bcursor, int E, int nb) {
  __shared__ int sh[512];
  int t = threadIdx.x;
  int v = (t < nb) ? bcount[t] : 0;
  sh[t] = v;
  __syncthreads();
  for (int off = 1; off < 512; off <<= 1) {
    int add = (t >= off) ? sh[t - off] : 0;
    __syncthreads();
    sh[t] += add;
    __syncthreads();
  }
  int excl = sh[t] - v;
  bbase[t] = excl;
  if (t < nb) bcursor[t] = excl;
  if (t == 511) bbase[512] = E;
}

// scatter edges into bucket-ordered packed array: low16 = src, hi bits = dst&127
__global__ __launch_bounds__(256) void k_scatter(const int* __restrict__ src, const int* __restrict__ dst,
                                                 int* __restrict__ bcursor, uint32_t* __restrict__ packed, int E) {
  int i = blockIdx.x * 256 + threadIdx.x;
  if (i < E) {
    int d = dst[i];
    int s = src[i];
    int slot = atomicAdd(&bcursor[d >> 7], 1);
    packed[slot] = (uint32_t)s | ((uint32_t)(d & 127) << 16);
  }
}

// per-bucket local CSR build: hist(128) -> scan -> local scatter; emits csr_src, row_ptr, dinv
__global__ __launch_bounds__(256) void k_bucket(const uint32_t* __restrict__ packed, const int* __restrict__ bbase,
                                                int* __restrict__ csr_src, int* __restrict__ row_ptr,
                                                float* __restrict__ dinv, int N, int E, int nb) {
  __shared__ int hist[128];
  __shared__ int scan[128];
  __shared__ int cur[128];
  int b = blockIdx.x;
  int t = threadIdx.x;
  int base = bbase[b], end = bbase[b + 1];
  if (t < 128) hist[t] = 0;
  __syncthreads();
  for (int i = base + t; i < end; i += 256)
    atomicAdd(&hist[packed[i] >> 16], 1);
  __syncthreads();
  int v = (t < 128) ? hist[t] : 0;
  if (t < 128) scan[t] = v;
  __syncthreads();
  for (int off = 1; off < 128; off <<= 1) {
    int add = (t < 128 && t >= off) ? scan[t - off] : 0;
    __syncthreads();
    if (t < 128) scan[t] += add;
    __syncthreads();
  }
  if (t < 128) {
    int excl = scan[t] - v;
    cur[t] = excl;
    int node = b * 128 + t;
    if (node < N) {
      row_ptr[node] = base + excl;
      dinv[node] = rsqrtf((float)(v + 1));  // +1 self-loop
    }
    if (b == nb - 1 && t == 0) row_ptr[N] = E;
  }
  __syncthreads();
  for (int i = base + t; i < end; i += 256) {
    uint32_t p = packed[i];
    int slot = atomicAdd(&cur[p >> 16], 1);
    csr_src[base + slot] = (int)(p & 0xffffu);
  }
}

// ---------------- W pre-pack into MFMA fragment order (hi/lo bf16) ----------------
__global__ __launch_bounds__(256) void k_wpack(const float* __restrict__ W1, const float* __restrict__ W2,
                                               ushort* __restrict__ buf) {
  int which = blockIdx.x >> 6;
  int idx = (blockIdx.x & 63) * 256 + threadIdx.x;  // 0..16383
  const float* W = which ? W2 : W1;
  ushort* hi = buf + which * 32768;
  ushort* lo = hi + 16384;
  int k = idx >> 7, n = idx & 127;
  float w = W[idx];
  uint32_t hb = f2bf(w);
  uint32_t lb = f2bf(w - bf_lo(hb));
  int j = n >> 4, t = k >> 5, ln = (n & 15) | (((k >> 3) & 3) << 4), i = k & 7;
  int p = (j * 4 + t) * 512 + ln * 8 + i;
  hi[p] = (ushort)hb;
  lo[p] = (ushort)lb;
}

// ---------------- MFMA GEMM: C[n x 128] = A[n x 128] @ W[128 x 128] ----------------
template <typename TA, bool OUT_BF16>
__global__ __launch_bounds__(256) void k_gemm_mfma(const TA* __restrict__ A,
                                                   const ushort* __restrict__ wpack,
                                                   void* __restrict__ Cp, int n) {
  const int lane = threadIdx.x & 63;
  const int gwave = (blockIdx.x * 256 + threadIdx.x) >> 6;
  const int rb = gwave * 32;
  if (rb >= n) return;
  const int lrow = lane & 15, lgrp = lane >> 4;
  const uint4* whi4 = (const uint4*)wpack;
  const uint4* wlo4 = (const uint4*)(wpack + 16384);

  const int r0 = rb + lrow, r1 = rb + 16 + lrow;
  const bool v0 = r0 < n, v1 = r1 < n;
  const int rc0 = v0 ? r0 : 0, rc1 = v1 ? r1 : 0;

  f32x4 acc0[8] = {};
  f32x4 acc1[8] = {};
  const uint4 zz = make_uint4(0, 0, 0, 0);

#pragma unroll
  for (int t = 0; t < 4; ++t) {
    FragU a0h, a0l, a1h, a1l;
    if constexpr (sizeof(TA) == 4) {  // fp32 input -> hi/lo split
      const float* ap0 = (const float*)A + (size_t)rc0 * CH + t * 32 + lgrp * 8;
      const float* ap1 = (const float*)A + (size_t)rc1 * CH + t * 32 + lgrp * 8;
      float4 xa = *(const float4*)ap0, xb = *(const float4*)(ap0 + 4);
      float4 ya = *(const float4*)ap1, yb = *(const float4*)(ap1 + 4);
      float xv[8] = {xa.x, xa.y, xa.z, xa.w, xb.x, xb.y, xb.z, xb.w};
      float yv[8] = {ya.x, ya.y, ya.z, ya.w, yb.x, yb.y, yb.z, yb.w};
#pragma unroll
      for (int i = 0; i < 8; ++i) {
        uint32_t h0 = f2bf(xv[i]);
        a0h.h[i] = (ushort)h0;
        a0l.h[i] = (ushort)f2bf(xv[i] - bf_lo(h0));
        uint32_t h1 = f2bf(yv[i]);
        a1h.h[i] = (ushort)h1;
        a1l.h[i] = (ushort)f2bf(yv[i] - bf_lo(h1));
      }
      if (!v0) { a0h.u = zz; a0l.u = zz; }
      if (!v1) { a1h.u = zz; a1l.u = zz; }
    } else {  // bf16 input
      a0h.u = v0 ? *(const uint4*)((const ushort*)A + (size_t)rc0 * CH + t * 32 + lgrp * 8) : zz;
      a1h.u = v1 ? *(const uint4*)((const ushort*)A + (size_t)rc1 * CH + t * 32 + lgrp * 8) : zz;
    }
#pragma unroll
    for (int j = 0; j < 8; ++j) {
      FragU wh, wl;
      wh.u = whi4[(j * 4 + t) * 64 + lane];
      wl.u = wlo4[(j * 4 + t) * 64 + lane];
      acc0[j] = __builtin_amdgcn_mfma_f32_16x16x32_bf16(wh.s, a0h.s, acc0[j], 0, 0, 0);
      acc0[j] = __builtin_amdgcn_mfma_f32_16x16x32_bf16(wl.s, a0h.s, acc0[j], 0, 0, 0);
      acc1[j] = __builtin_amdgcn_mfma_f32_16x16x32_bf16(wh.s, a1h.s, acc1[j], 0, 0, 0);
      acc1[j] = __builtin_amdgcn_mfma_f32_16x16x32_bf16(wl.s, a1h.s, acc1[j], 0, 0, 0);
      if constexpr (sizeof(TA) == 4) {
        acc0[j] = __builtin_amdgcn_mfma_f32_16x16x32_bf16(wh.s, a0l.s, acc0[j], 0, 0, 0);
        acc1[j] = __builtin_amdgcn_mfma_f32_16x16x32_bf16(wh.s, a1l.s, acc1[j], 0, 0, 0);
      }
    }
  }

  if (v0) {
#pragma unroll
    for (int j = 0; j < 8; ++j) {
      if constexpr (OUT_BF16) {
        uint2 o;
        o.x = f2bf(acc0[j][0]) | (f2bf(acc0[j][1]) << 16);
        o.y = f2bf(acc0[j][2]) | (f2bf(acc0[j][3]) << 16);
        *(uint2*)&((ushort*)Cp)[(size_t)r0 * CH + j * 16 + lgrp * 4] = o;
      } else {
        float4 o = make_float4(acc0[j][0], acc0[j][1], acc0[j][2], acc0[j][3]);
        *(float4*)&((float*)Cp)[(size_t)r0 * CH + j * 16 + lgrp * 4] = o;
      }
    }
  }
  if (v1) {
#pragma unroll
    for (int j = 0; j < 8; ++j) {
      if constexpr (OUT_BF16) {
        uint2 o;
        o.x = f2bf(acc1[j][0]) | (f2bf(acc1[j][1]) << 16);
        o.y = f2bf(acc1[j][2]) | (f2bf(acc1[j][3]) << 16);
        *(uint2*)&((ushort*)Cp)[(size_t)r1 * CH + j * 16 + lgrp * 4] = o;
      } else {
        float4 o = make_float4(acc1[j][0], acc1[j][1], acc1[j][2], acc1[j][3]);
        *(float4*)&((float*)Cp)[(size_t)r1 * CH + j * 16 + lgrp * 4] = o;
      }
    }
  }
}

// ---------------- aggregation: out[v] = relu(sum norm * h[s] + self + b) ----------------
template <bool OUT_BF16>
__global__ __launch_bounds__(256) void k_agg(const ushort* __restrict__ h, const int* __restrict__ row_ptr,
                                             const int* __restrict__ csr_src, const float* __restrict__ dinv,
                                             const float* __restrict__ b, void* __restrict__ outp, int n) {
  int v = (blockIdx.x * 256 + threadIdx.x) >> 6;
  int lane = threadIdx.x & 63;
  if (v >= n) return;
  v = __builtin_amdgcn_readfirstlane(v);
  float dv = dinv[v];
  uint32_t us = *(const uint32_t*)&h[(size_t)v * CH + 2 * lane];
  float self = dv * dv;
  float acc0 = bf_lo(us) * self;
  float acc1 = bf_hi(us) * self;
  int j = row_ptr[v], end = row_ptr[v + 1];
  for (; j + 3 < end; j += 4) {
    int s0 = csr_src[j], s1 = csr_src[j + 1], s2 = csr_src[j + 2], s3 = csr_src[j + 3];
    float w0 = dinv[s0] * dv, w1 = dinv[s1] * dv, w2 = dinv[s2] * dv, w3 = dinv[s3] * dv;
    uint32_t u0 = *(const uint32_t*)&h[(size_t)s0 * CH + 2 * lane];
    uint32_t u1 = *(const uint32_t*)&h[(size_t)s1 * CH + 2 * lane];
    uint32_t u2 = *(const uint32_t*)&h[(size_t)s2 * CH + 2 * lane];
    uint32_t u3 = *(const uint32_t*)&h[(size_t)s3 * CH + 2 * lane];
    acc0 += bf_lo(u0) * w0; acc1 += bf_hi(u0) * w0;
    acc0 += bf_lo(u1) * w1; acc1 += bf_hi(u1) * w1;
    acc0 += bf_lo(u2) * w2; acc1 += bf_hi(u2) * w2;
    acc0 += bf_lo(u3) * w3; acc1 += bf_hi(u3) * w3;
  }
  for (; j < end; ++j) {
    int s0 = csr_src[j];
    float w0 = dinv[s0] * dv;
    uint32_t u0 = *(const uint32_t*)&h[(size_t)s0 * CH + 2 * lane];
    acc0 += bf_lo(u0) * w0; acc1 += bf_hi(u0) * w0;
  }
  float2 bb = *(const float2*)&b[2 * lane];
  acc0 = fmaxf(acc0 + bb.x, 0.f);
  acc1 = fmaxf(acc1 + bb.y, 0.f);
  if constexpr (OUT_BF16) {
    ((uint32_t*)outp)[(size_t)v * 64 + lane] = f2bf(acc0) | (f2bf(acc1) << 16);
  } else {
    ((float2*)outp)[(size_t)v * 64 + lane] = make_float2(acc0, acc1);
  }
}

// ---------------- launch ----------------

extern "C" void kernel_launch(void* const* d_in, const int* in_sizes, int n_in,
                              void* d_out, int out_size, void* d_ws, size_t ws_size,
                              hipStream_t stream) {
  const float* x  = (const float*)d_in[0];
  const int*   ei = (const int*)d_in[1];
  const float* W1 = (const float*)d_in[2];
  const float* b1 = (const float*)d_in[3];
  const float* W2 = (const float*)d_in[4];
  const float* b2 = (const float*)d_in[5];
  float* out = (float*)d_out;

  const int N = in_sizes[0] / CH;
  const int E = in_sizes[1] / 2;
  const int* src = ei;
  const int* dst = ei + E;
  const int nb = (N + 127) / 128;  // coarse buckets

  char* ws = (char*)d_ws;
  size_t off = 0;
  auto alloc = [&](size_t bytes) -> void* {
    void* p = ws + off;
    off += (bytes + 255) & ~(size_t)255;
    return p;
  };
  int*      bcount  = (int*)alloc(512 * 4);
  int*      bbase   = (int*)alloc(513 * 4);
  int*      bcursor = (int*)alloc(512 * 4);
  uint32_t* packed  = (uint32_t*)alloc((size_t)E * 4);
  int*      row_ptr = (int*)alloc((size_t)(N + 1) * 4);
  int*      csr_src = (int*)alloc((size_t)E * 4);
  float*    dinv    = (float*)alloc((size_t)N * 4);
  ushort*   wpack   = (ushort*)alloc(4 * 16384 * 2);      // [hi1|lo1|hi2|lo2]
  ushort*   h       = (ushort*)alloc((size_t)N * CH * 2);  // bf16
  ushort*   y1      = (ushort*)alloc((size_t)N * CH * 2);  // bf16
  (void)ws_size;

  const int gE = (E + 255) / 256;

  k_zero<<<2, 256, 0, stream>>>(bcount, 512);
  k_hist<<<(E + 1023) / 1024, 256, 0, stream>>>(dst, bcount, E);
  k_scanb<<<1, 512, 0, stream>>>(bcount, bbase, bcursor, E, nb);
  k_scatter<<<gE, 256, 0, stream>>>(src, dst, bcursor, packed, E);
  k_bucket<<<nb, 256, 0, stream>>>(packed, bbase, csr_src, row_ptr, dinv, N, E, nb);
  k_wpack<<<128, 256, 0, stream>>>(W1, W2, wpack);

  const int waves = (N + 31) / 32;
  const int gG = (waves + 3) / 4;
  const int gA = (N + 3) / 4;

  // layer 1
  k_gemm_mfma<float, true><<<gG, 256, 0, stream>>>(x, wpack, h, N);
  k_agg<true><<<gA, 256, 0, stream>>>(h, row_ptr, csr_src, dinv, b1, y1, N);
  // layer 2
  k_gemm_mfma<ushort, true><<<gG, 256, 0, stream>>>(y1, wpack + 32768, h, N);
  k_agg<false><<<gA, 256, 0, stream>>>(h, row_ptr, csr_src, dinv, b2, out, N);
}

// Round 5
// 131.825 us; speedup vs baseline: 2.7080x; 2.7080x over previous
//
#include <hip/hip_runtime.h>
#include <hip/hip_bf16.h>
#include <cstdint>

#define CH 128
#define NB 512          // coarse buckets (128 nodes each); N < 65536 for packing
#define SCHUNK 4096     // edges per scatter/hist block

typedef __attribute__((ext_vector_type(8))) short short8;
typedef __attribute__((ext_vector_type(4))) float f32x4;

union FragU {
  uint4 u;
  short8 s;
  ushort h[8];
};

// ---------------- bf16 helpers ----------------
__device__ __forceinline__ float bf_lo(uint32_t u) { return __uint_as_float(u << 16); }
__device__ __forceinline__ float bf_hi(uint32_t u) { return __uint_as_float(u & 0xffff0000u); }
__device__ __forceinline__ uint32_t f2bf(float f) {  // RNE, result in low 16
  uint32_t u = __float_as_uint(f);
  u += 0x7fff + ((u >> 16) & 1);
  return u >> 16;
}

// ---------------- CSR build: contention-free counting sort ----------------
// 1) per-block LDS histogram -> counts[bucket * nblk + blk]  (bucket-major)
__global__ __launch_bounds__(256) void k_hist2(const int* __restrict__ dst, int* __restrict__ counts,
                                               int E, int nblk) {
  __shared__ int sh[NB];
  int t = threadIdx.x, blk = blockIdx.x;
  for (int i = t; i < NB; i += 256) sh[i] = 0;
  __syncthreads();
  int base = blk * SCHUNK, lim = min(base + SCHUNK, E);
  for (int i = base + t; i < lim; i += 256) atomicAdd(&sh[dst[i] >> 7], 1);
  __syncthreads();
  for (int i = t; i < NB; i += 256) counts[i * nblk + blk] = sh[i];
}

// 2a) scan within 1024-blocks
__global__ __launch_bounds__(1024) void k_scan1(const int* __restrict__ in, int* __restrict__ excl,
                                                int* __restrict__ blocksum, int n) {
  __shared__ int sd[1024];
  int tid = threadIdx.x;
  int i = blockIdx.x * 1024 + tid;
  int v = (i < n) ? in[i] : 0;
  int x = v;
  sd[tid] = x;
  __syncthreads();
  for (int off = 1; off < 1024; off <<= 1) {
    int t = (tid >= off) ? sd[tid - off] : 0;
    __syncthreads();
    x += t;
    sd[tid] = x;
    __syncthreads();
  }
  if (i < n) excl[i] = x - v;
  if (tid == 1023) blocksum[blockIdx.x] = x;
}

// 2b) scan block sums (1 block, 128 threads; nb <= 128)
__global__ void k_scan2b(int* __restrict__ bs, int nb) {
  __shared__ int sh[128];
  int t = threadIdx.x;
  int v = (t < nb) ? bs[t] : 0;
  sh[t] = v;
  __syncthreads();
  for (int off = 1; off < 128; off <<= 1) {
    int add = (t >= off) ? sh[t - off] : 0;
    __syncthreads();
    sh[t] += add;
    __syncthreads();
  }
  if (t < nb) bs[t] = sh[t] - v;
}

// 2c) add block offsets in place; emit bbase[b] = excl[b*nblk], bbase[NB] = E
__global__ __launch_bounds__(256) void k_scan3b(int* __restrict__ excl, const int* __restrict__ boff,
                                                int* __restrict__ bbase, int total, int nblk, int E) {
  int i = blockIdx.x * 256 + threadIdx.x;
  if (i < total) {
    int val = excl[i] + boff[i >> 10];
    excl[i] = val;
    if (i % nblk == 0) bbase[i / nblk] = val;
  }
  if (i == 0) bbase[NB] = E;
}

// 3) scatter: block base from scanned counts, local rank via LDS atomics (no global atomics)
__global__ __launch_bounds__(256) void k_scatter3(const int* __restrict__ src, const int* __restrict__ dst,
                                                  const int* __restrict__ excl, uint32_t* __restrict__ packed,
                                                  int E, int nblk) {
  __shared__ int lcur[NB];
  int t = threadIdx.x, blk = blockIdx.x;
  for (int i = t; i < NB; i += 256) lcur[i] = excl[i * nblk + blk];
  __syncthreads();
  int base = blk * SCHUNK, lim = min(base + SCHUNK, E);
  for (int i = base + t; i < lim; i += 256) {
    int d = dst[i], s = src[i];
    int slot = atomicAdd(&lcur[d >> 7], 1);
    packed[slot] = (uint32_t)s | ((uint32_t)(d & 127) << 16);
  }
}

// 4) per-bucket local CSR build: hist(128) -> scan -> local scatter; emits csr_src, row_ptr, dinv
__global__ __launch_bounds__(256) void k_bucket(const uint32_t* __restrict__ packed, const int* __restrict__ bbase,
                                                int* __restrict__ csr_src, int* __restrict__ row_ptr,
                                                float* __restrict__ dinv, int N, int E, int nb) {
  __shared__ int hist[128];
  __shared__ int scan[128];
  __shared__ int cur[128];
  int b = blockIdx.x;
  int t = threadIdx.x;
  int base = bbase[b], end = bbase[b + 1];
  if (t < 128) hist[t] = 0;
  __syncthreads();
  for (int i = base + t; i < end; i += 256)
    atomicAdd(&hist[packed[i] >> 16], 1);
  __syncthreads();
  int v = (t < 128) ? hist[t] : 0;
  if (t < 128) scan[t] = v;
  __syncthreads();
  for (int off = 1; off < 128; off <<= 1) {
    int add = (t < 128 && t >= off) ? scan[t - off] : 0;
    __syncthreads();
    if (t < 128) scan[t] += add;
    __syncthreads();
  }
  if (t < 128) {
    int excl = scan[t] - v;
    cur[t] = excl;
    int node = b * 128 + t;
    if (node < N) {
      row_ptr[node] = base + excl;
      dinv[node] = rsqrtf((float)(v + 1));  // +1 self-loop
    }
    if (b == nb - 1 && t == 0) row_ptr[N] = E;
  }
  __syncthreads();
  for (int i = base + t; i < end; i += 256) {
    uint32_t p = packed[i];
    int slot = atomicAdd(&cur[p >> 16], 1);
    csr_src[base + slot] = (int)(p & 0xffffu);
  }
}

// ---------------- W pre-pack into MFMA fragment order (hi/lo bf16) ----------------
__global__ __launch_bounds__(256) void k_wpack(const float* __restrict__ W1, const float* __restrict__ W2,
                                               ushort* __restrict__ buf) {
  int which = blockIdx.x >> 6;
  int idx = (blockIdx.x & 63) * 256 + threadIdx.x;  // 0..16383
  const float* W = which ? W2 : W1;
  ushort* hi = buf + which * 32768;
  ushort* lo = hi + 16384;
  int k = idx >> 7, n = idx & 127;
  float w = W[idx];
  uint32_t hb = f2bf(w);
  uint32_t lb = f2bf(w - bf_lo(hb));
  int j = n >> 4, t = k >> 5, ln = (n & 15) | (((k >> 3) & 3) << 4), i = k & 7;
  int p = (j * 4 + t) * 512 + ln * 8 + i;
  hi[p] = (ushort)hb;
  lo[p] = (ushort)lb;
}

// ---------------- MFMA GEMM: C[n x 128] = A[n x 128] @ W[128 x 128] ----------------
template <typename TA, bool OUT_BF16>
__global__ __launch_bounds__(256) void k_gemm_mfma(const TA* __restrict__ A,
                                                   const ushort* __restrict__ wpack,
                                                   void* __restrict__ Cp, int n) {
  const int lane = threadIdx.x & 63;
  const int gwave = (blockIdx.x * 256 + threadIdx.x) >> 6;
  const int rb = gwave * 32;
  if (rb >= n) return;
  const int lrow = lane & 15, lgrp = lane >> 4;
  const uint4* whi4 = (const uint4*)wpack;
  const uint4* wlo4 = (const uint4*)(wpack + 16384);

  const int r0 = rb + lrow, r1 = rb + 16 + lrow;
  const bool v0 = r0 < n, v1 = r1 < n;
  const int rc0 = v0 ? r0 : 0, rc1 = v1 ? r1 : 0;

  f32x4 acc0[8] = {};
  f32x4 acc1[8] = {};
  const uint4 zz = make_uint4(0, 0, 0, 0);

#pragma unroll
  for (int t = 0; t < 4; ++t) {
    FragU a0h, a0l, a1h, a1l;
    if constexpr (sizeof(TA) == 4) {  // fp32 input -> hi/lo split
      const float* ap0 = (const float*)A + (size_t)rc0 * CH + t * 32 + lgrp * 8;
      const float* ap1 = (const float*)A + (size_t)rc1 * CH + t * 32 + lgrp * 8;
      float4 xa = *(const float4*)ap0, xb = *(const float4*)(ap0 + 4);
      float4 ya = *(const float4*)ap1, yb = *(const float4*)(ap1 + 4);
      float xv[8] = {xa.x, xa.y, xa.z, xa.w, xb.x, xb.y, xb.z, xb.w};
      float yv[8] = {ya.x, ya.y, ya.z, ya.w, yb.x, yb.y, yb.z, yb.w};
#pragma unroll
      for (int i = 0; i < 8; ++i) {
        uint32_t h0 = f2bf(xv[i]);
        a0h.h[i] = (ushort)h0;
        a0l.h[i] = (ushort)f2bf(xv[i] - bf_lo(h0));
        uint32_t h1 = f2bf(yv[i]);
        a1h.h[i] = (ushort)h1;
        a1l.h[i] = (ushort)f2bf(yv[i] - bf_lo(h1));
      }
      if (!v0) { a0h.u = zz; a0l.u = zz; }
      if (!v1) { a1h.u = zz; a1l.u = zz; }
    } else {  // bf16 input
      a0h.u = v0 ? *(const uint4*)((const ushort*)A + (size_t)rc0 * CH + t * 32 + lgrp * 8) : zz;
      a1h.u = v1 ? *(const uint4*)((const ushort*)A + (size_t)rc1 * CH + t * 32 + lgrp * 8) : zz;
    }
#pragma unroll
    for (int j = 0; j < 8; ++j) {
      FragU wh, wl;
      wh.u = whi4[(j * 4 + t) * 64 + lane];
      wl.u = wlo4[(j * 4 + t) * 64 + lane];
      acc0[j] = __builtin_amdgcn_mfma_f32_16x16x32_bf16(wh.s, a0h.s, acc0[j], 0, 0, 0);
      acc0[j] = __builtin_amdgcn_mfma_f32_16x16x32_bf16(wl.s, a0h.s, acc0[j], 0, 0, 0);
      acc1[j] = __builtin_amdgcn_mfma_f32_16x16x32_bf16(wh.s, a1h.s, acc1[j], 0, 0, 0);
      acc1[j] = __builtin_amdgcn_mfma_f32_16x16x32_bf16(wl.s, a1h.s, acc1[j], 0, 0, 0);
      if constexpr (sizeof(TA) == 4) {
        acc0[j] = __builtin_amdgcn_mfma_f32_16x16x32_bf16(wh.s, a0l.s, acc0[j], 0, 0, 0);
        acc1[j] = __builtin_amdgcn_mfma_f32_16x16x32_bf16(wh.s, a1l.s, acc1[j], 0, 0, 0);
      }
    }
  }

  if (v0) {
#pragma unroll
    for (int j = 0; j < 8; ++j) {
      if constexpr (OUT_BF16) {
        uint2 o;
        o.x = f2bf(acc0[j][0]) | (f2bf(acc0[j][1]) << 16);
        o.y = f2bf(acc0[j][2]) | (f2bf(acc0[j][3]) << 16);
        *(uint2*)&((ushort*)Cp)[(size_t)r0 * CH + j * 16 + lgrp * 4] = o;
      } else {
        float4 o = make_float4(acc0[j][0], acc0[j][1], acc0[j][2], acc0[j][3]);
        *(float4*)&((float*)Cp)[(size_t)r0 * CH + j * 16 + lgrp * 4] = o;
      }
    }
  }
  if (v1) {
#pragma unroll
    for (int j = 0; j < 8; ++j) {
      if constexpr (OUT_BF16) {
        uint2 o;
        o.x = f2bf(acc1[j][0]) | (f2bf(acc1[j][1]) << 16);
        o.y = f2bf(acc1[j][2]) | (f2bf(acc1[j][3]) << 16);
        *(uint2*)&((ushort*)Cp)[(size_t)r1 * CH + j * 16 + lgrp * 4] = o;
      } else {
        float4 o = make_float4(acc1[j][0], acc1[j][1], acc1[j][2], acc1[j][3]);
        *(float4*)&((float*)Cp)[(size_t)r1 * CH + j * 16 + lgrp * 4] = o;
      }
    }
  }
}

// ---------------- aggregation: out[v] = relu(sum norm * h[s] + self + b) ----------------
template <bool OUT_BF16>
__global__ __launch_bounds__(256) void k_agg(const ushort* __restrict__ h, const int* __restrict__ row_ptr,
                                             const int* __restrict__ csr_src, const float* __restrict__ dinv,
                                             const float* __restrict__ b, void* __restrict__ outp, int n) {
  int v = (blockIdx.x * 256 + threadIdx.x) >> 6;
  int lane = threadIdx.x & 63;
  if (v >= n) return;
  v = __builtin_amdgcn_readfirstlane(v);
  float dv = dinv[v];
  uint32_t us = *(const uint32_t*)&h[(size_t)v * CH + 2 * lane];
  float self = dv * dv;
  float acc0 = bf_lo(us) * self;
  float acc1 = bf_hi(us) * self;
  int j = row_ptr[v], end = row_ptr[v + 1];
  for (; j + 3 < end; j += 4) {
    int s0 = csr_src[j], s1 = csr_src[j + 1], s2 = csr_src[j + 2], s3 = csr_src[j + 3];
    float w0 = dinv[s0] * dv, w1 = dinv[s1] * dv, w2 = dinv[s2] * dv, w3 = dinv[s3] * dv;
    uint32_t u0 = *(const uint32_t*)&h[(size_t)s0 * CH + 2 * lane];
    uint32_t u1 = *(const uint32_t*)&h[(size_t)s1 * CH + 2 * lane];
    uint32_t u2 = *(const uint32_t*)&h[(size_t)s2 * CH + 2 * lane];
    uint32_t u3 = *(const uint32_t*)&h[(size_t)s3 * CH + 2 * lane];
    acc0 += bf_lo(u0) * w0; acc1 += bf_hi(u0) * w0;
    acc0 += bf_lo(u1) * w1; acc1 += bf_hi(u1) * w1;
    acc0 += bf_lo(u2) * w2; acc1 += bf_hi(u2) * w2;
    acc0 += bf_lo(u3) * w3; acc1 += bf_hi(u3) * w3;
  }
  for (; j < end; ++j) {
    int s0 = csr_src[j];
    float w0 = dinv[s0] * dv;
    uint32_t u0 = *(const uint32_t*)&h[(size_t)s0 * CH + 2 * lane];
    acc0 += bf_lo(u0) * w0; acc1 += bf_hi(u0) * w0;
  }
  float2 bb = *(const float2*)&b[2 * lane];
  acc0 = fmaxf(acc0 + bb.x, 0.f);
  acc1 = fmaxf(acc1 + bb.y, 0.f);
  if constexpr (OUT_BF16) {
    ((uint32_t*)outp)[(size_t)v * 64 + lane] = f2bf(acc0) | (f2bf(acc1) << 16);
  } else {
    ((float2*)outp)[(size_t)v * 64 + lane] = make_float2(acc0, acc1);
  }
}

// ---------------- launch ----------------

extern "C" void kernel_launch(void* const* d_in, const int* in_sizes, int n_in,
                              void* d_out, int out_size, void* d_ws, size_t ws_size,
                              hipStream_t stream) {
  const float* x  = (const float*)d_in[0];
  const int*   ei = (const int*)d_in[1];
  const float* W1 = (const float*)d_in[2];
  const float* b1 = (const float*)d_in[3];
  const float* W2 = (const float*)d_in[4];
  const float* b2 = (const float*)d_in[5];
  float* out = (float*)d_out;

  const int N = in_sizes[0] / CH;
  const int E = in_sizes[1] / 2;
  const int* src = ei;
  const int* dst = ei + E;
  const int nb = (N + 127) / 128;           // used coarse buckets (<= NB)
  const int nblk = (E + SCHUNK - 1) / SCHUNK;  // scatter blocks
  const int total = NB * nblk;              // counts array size
  const int nsb = (total + 1023) / 1024;    // scan blocks (<=128)

  char* ws = (char*)d_ws;
  size_t off = 0;
  auto alloc = [&](size_t bytes) -> void* {
    void* p = ws + off;
    off += (bytes + 255) & ~(size_t)255;
    return p;
  };
  int*      counts  = (int*)alloc((size_t)total * 4);  // scanned in place
  int*      blocksum= (int*)alloc(128 * 4);
  int*      bbase   = (int*)alloc((NB + 1) * 4);
  uint32_t* packed  = (uint32_t*)alloc((size_t)E * 4);
  int*      row_ptr = (int*)alloc((size_t)(N + 1) * 4);
  int*      csr_src = (int*)alloc((size_t)E * 4);
  float*    dinv    = (float*)alloc((size_t)N * 4);
  ushort*   wpack   = (ushort*)alloc(4 * 16384 * 2);      // [hi1|lo1|hi2|lo2]
  ushort*   h       = (ushort*)alloc((size_t)N * CH * 2);  // bf16
  ushort*   y1      = (ushort*)alloc((size_t)N * CH * 2);  // bf16
  (void)ws_size;

  k_hist2<<<nblk, 256, 0, stream>>>(dst, counts, E, nblk);
  k_scan1<<<nsb, 1024, 0, stream>>>(counts, counts, blocksum, total);
  k_scan2b<<<1, 128, 0, stream>>>(blocksum, nsb);
  k_scan3b<<<(total + 255) / 256, 256, 0, stream>>>(counts, blocksum, bbase, total, nblk, E);
  k_scatter3<<<nblk, 256, 0, stream>>>(src, dst, counts, packed, E, nblk);
  k_bucket<<<nb, 256, 0, stream>>>(packed, bbase, csr_src, row_ptr, dinv, N, E, nb);
  k_wpack<<<128, 256, 0, stream>>>(W1, W2, wpack);

  const int waves = (N + 31) / 32;
  const int gG = (waves + 3) / 4;
  const int gA = (N + 3) / 4;

  // layer 1
  k_gemm_mfma<float, true><<<gG, 256, 0, stream>>>(x, wpack, h, N);
  k_agg<true><<<gA, 256, 0, stream>>>(h, row_ptr, csr_src, dinv, b1, y1, N);
  // layer 2
  k_gemm_mfma<ushort, true><<<gG, 256, 0, stream>>>(y1, wpack + 32768, h, N);
  k_agg<false><<<gA, 256, 0, stream>>>(h, row_ptr, csr_src, dinv, b2, out, N);
}